// Round 11
// baseline (79.302 us; speedup 1.0000x reference)
//
#include <hip/hip_runtime.h>
#include <math.h>

#define KK 40
#define HH 16
#define DD 128
#define NN 512
#define X0C 0.085f
#define LOG2E 1.4426950408889634f
#define LN2f 0.6931471805599453f
#define SCB 17.0f   // per-step 2^-17 scaling folded into P~

// ws layout (float offsets). A-tables TRANSPOSED ([o][r]).
enum {
  OFF_AW   = 0,                  // 512*16  fwd RNN drive
  OFF_BW   = OFF_AW + NN*HH,     // 512*16  bwd RNN drive
  OFF_WPB  = OFF_BW + NN*HH,     // 512*40  UwB @ W
  OFF_WBG  = OFF_WPB + NN*KK,    // 512*40  rowsum WlinB[words]
  OFF_TB   = OFF_WBG + NN*KK,    // 40*40
  OFF_H    = OFF_TB + KK*KK,     // 514*16
  OFF_HP   = OFF_H + 514*HH,     // 514*16
  OFF_A0   = OFF_HP + 514*HH,    // 40*40 x4 Taylor tables [o][r]
  OFF_A1   = OFF_A0 + KK*KK,
  OFF_A2   = OFF_A1 + KK*KK,
  OFF_A3   = OFF_A2 + KK*KK,
  OFF_FIN  = OFF_A3 + KK*KK,     // 40
  OFF_LACC = OFF_FIN + KK,       // 128
  OFF_VL   = OFF_LACC + 128,     // 40
  OFF_FLG  = OFF_VL + 40,        // 768 uints (flags + counters), memset to 0
  OFF_D    = OFF_FLG + 768,      // 64000*4 sigma-derivative tables
  WS_FLOATS = OFF_D + KK*KK*KK*4
};

// flag indices (uint offsets within OFF_FLG)
#define FG    0     // 512 per-word gather flags
#define FTB   512   // TB done
#define FD    520   // 40 D-row flags
#define FRC   560   // 128 RNN chunk flags (64 fwd, 64 bwd)
#define FMAC  688   // 40 per-o MAC flags
#define FCTR  728   // finisher: main(0) + 8 sub(1..8)

#define NB_GATHER  NN            // 512
#define B_TB       NN            // 512
#define B_D0       (NN + 1)      // 513
#define B_RNN0     (NN + 1 + KK) // 553
#define B_MAC0     (B_RNN0 + 8)  // 561
#define B_SCAN0    (B_MAC0 + KK) // 601
#define NBLKS      (B_SCAN0 + 128) // 729

__device__ __forceinline__ float sigm(float x) {
  return 1.f / (1.f + __expf(-x));
}
__device__ __forceinline__ void waitflag(unsigned* f) {
  while (__hip_atomic_load(f, __ATOMIC_RELAXED, __HIP_MEMORY_SCOPE_AGENT) == 0u)
    __builtin_amdgcn_s_sleep(4);
}

__global__ __launch_bounds__(256, 3) void fused(
    const float* __restrict__ E, const float* __restrict__ M,
    const float* __restrict__ MP, const float* __restrict__ T,
    const float* __restrict__ UA, const float* __restrict__ UB,
    const float* __restrict__ WlinA, const float* __restrict__ WlinB,
    const int* __restrict__ words, float* __restrict__ ws, float* __restrict__ out)
{
  __shared__ __align__(16) float arena[6976];   // 27.9 KB, carved per role
  __shared__ int lastFlag;
  unsigned* flg = (unsigned*)(ws + OFF_FLG);
  int b = blockIdx.x, tid = threadIdx.x;
  int lane = tid & 63, widx = tid >> 6;

  if (b < NB_GATHER) {
    // ---------- per-word gathers ----------
    float* wrow = arena;                 // [128]
    int w = words[b];
    if (tid < DD) wrow[tid] = E[w*DD + tid];
    if (tid < KK) {                      // WBg[b,u] = sum_s WlinB[w, s*40+u]
      const float* wb = WlinB + (size_t)w*(KK*KK) + tid;
      float acc = 0.f;
      #pragma unroll 8
      for (int s = 0; s < KK; ++s) acc += wb[s*KK];
      ws[OFF_WBG + b*KK + tid] = acc;
    }
    __syncthreads();
    if (tid < 16) {                      // aw
      float acc = 0.f; const float* mr = M + tid*145 + 17;
      for (int d = 0; d < DD; ++d) acc += mr[d]*wrow[d];
      ws[OFF_AW + b*HH + tid] = acc;
    } else if (tid < 32) {               // bw
      int j = tid - 16; float acc = 0.f; const float* mr = MP + j*145 + 1;
      for (int d = 0; d < DD; ++d) acc += mr[d]*wrow[d];
      ws[OFF_BW + b*HH + j] = acc;
    } else if (tid < 72) {               // wpartB
      int o = tid - 32; float acc = 0.f; const float* ur = UB + o*289 + 145;
      for (int d = 0; d < DD; ++d) acc += ur[d]*wrow[d];
      ws[OFF_WPB + b*KK + o] = acc;
    }
    __syncthreads();
    if (tid == 0) { __threadfence(); atomicExch(&flg[FG + b], 1u); }

  } else if (b == B_TB) {
    // ---------- TB = UtB @ T^T ----------
    float* Tl = arena;                   // [5120]
    for (int idx = tid; idx < KK*DD; idx += 256) Tl[idx] = T[idx];
    __syncthreads();
    for (int o2 = tid; o2 < KK*KK; o2 += 256) {
      int r = o2 / KK, s = o2 % KK;
      const float* ur = UB + r*289 + 145;
      float acc = 0.f;
      for (int d = 0; d < DD; ++d) acc += ur[d]*Tl[s*DD + d];
      ws[OFF_TB + o2] = acc;
    }
    __syncthreads();
    if (tid == 0) { __threadfence(); atomicExch(&flg[FTB], 1u); }

  } else if (b < B_RNN0) {
    // ---------- sigma-derivative tables, r = b-513 ----------
    int r = b - B_D0;
    float* ur = arena;                   // [256]
    float* sa = arena + 256;             // [40]
    float* ta = arena + 296;             // [40]
    if (tid < DD) ur[tid] = UA[r*289 + 17 + tid];
    else if (tid < 2*DD) ur[tid] = UA[r*289 + 145 + (tid - DD)];
    __syncthreads();
    if (tid < KK) {
      float acc = 0.f; const float* tr = T + tid*DD;
      for (int d = 0; d < DD; ++d) acc += ur[d]*tr[d];
      sa[tid] = acc;
    } else if (tid >= 64 && tid < 64 + KK) {
      int s = tid - 64; float acc = 0.f; const float* tr = T + s*DD;
      for (int d = 0; d < DD; ++d) acc += ur[DD + d]*tr[d];
      ta[s] = acc;
    }
    __syncthreads();
    float4* dp = (float4*)(ws + OFF_D) + (size_t)r*1600;
    for (int st = tid; st < KK*KK; st += 256) {
      int s = st / KK, u = st - s*KK;
      float y = X0C + sa[s] + ta[u];
      float sg = sigm(y);
      float s1 = sg*(1.f - sg);
      float d2 = s1*(1.f - 2.f*sg)*0.5f;
      float d3 = s1*(1.f - 6.f*sg*(1.f - sg))*(1.f/6.f);
      dp[st] = make_float4(sg, s1, d2, d3);
    }
    __syncthreads();
    if (tid == 0) { __threadfence(); atomicExch(&flg[FD + r], 1u); }

  } else if (b < B_MAC0) {
    // ---------- RNN: 16 chunks per block ----------
    int rb = b - B_RNN0;
    int row = tid & 15;
    int g = rb*16 + (tid >> 4);          // 0..127
    int dirb = g >> 6;
    int c = g & 63;
    const float* Mat = dirb ? MP : M;
    const float* drv = ws + (dirb ? OFF_BW : OFF_AW);
    float* outh = ws + (dirb ? OFF_HP : OFF_H);
    float base = Mat[row*145];
    int hoff = dirb ? 129 : 1;
    float mh[HH];
    #pragma unroll
    for (int k = 0; k < HH; ++k) mh[k] = Mat[row*145 + hoff + k];
    // poll the 16 drive rows this chunk reads (clamped)
    int start = dirb ? 8*c : (8*c - 8);
    int prow = min(max(start + row, 0), NN - 1);
    waitflag(&flg[FG + prow]);
    __threadfence();
    float dr[16];
    #pragma unroll
    for (int j = 0; j < 16; ++j) {
      int i = dirb ? (8*c + 15 - j) : (8*c - 8 + j);
      int ic = min(max(i, 0), NN - 1);
      dr[j] = drv[ic*HH + row];
    }
    float h = 0.f;
    #pragma unroll
    for (int j = 0; j < 16; ++j) {
      int i = dirb ? (8*c + 15 - j) : (8*c - 8 + j);
      bool valid = (i >= 0) && (i < NN);
      float acc = base + dr[j];
      #pragma unroll
      for (int k = 0; k < HH; ++k) acc += mh[k] * __shfl(h, k, 16);
      float h2 = sigm(acc);
      if (valid) h = h2;
      if (valid && j >= 8) outh[(i + 1)*HH + row] = h;
    }
    if (rb == 0 && tid < 16) {           // boundary zeros (before fence)
      ws[OFF_H + tid] = 0.f;  ws[OFF_H + 513*HH + tid] = 0.f;
      ws[OFF_HP + tid] = 0.f; ws[OFF_HP + 513*HH + tid] = 0.f;
    }
    __threadfence();
    if ((tid & 15) == 0) atomicExch(&flg[FRC + g], 1u);

  } else if (b < B_SCAN0) {
    // ---------- MAC: one o per block, wave q handles r = q*10..q*10+9 ----------
    int o = b - B_MAC0;
    int q = widx;
    float wreg[25];
    #pragma unroll
    for (int k = 0; k < 25; ++k) wreg[k] = WlinA[o*1600 + lane + 64*k];
    if (lane < 10) waitflag(&flg[FD + q*10 + lane]);
    __threadfence();
    for (int rr = 0; rr < 10; ++rr) {
      int r = q*10 + rr;
      const float4* dp = (const float4*)(ws + OFF_D) + (size_t)r*1600;
      float a0 = 0, a1 = 0, a2 = 0, a3 = 0;
      #pragma unroll
      for (int k = 0; k < 25; ++k) {
        float4 d = dp[lane + 64*k];
        float wl = wreg[k];
        a0 += d.x*wl; a1 += d.y*wl; a2 += d.z*wl; a3 += d.w*wl;
      }
      #pragma unroll
      for (int m = 1; m <= 32; m <<= 1) {
        a0 += __shfl_xor(a0, m); a1 += __shfl_xor(a1, m);
        a2 += __shfl_xor(a2, m); a3 += __shfl_xor(a3, m);
      }
      if (lane == 0) {                   // transposed write [o][r]
        ws[OFF_A0 + o*KK + r] = a0; ws[OFF_A1 + o*KK + r] = a1;
        ws[OFF_A2 + o*KK + r] = a2; ws[OFF_A3 + o*KK + r] = a3;
      }
    }
    __syncthreads();
    if (tid == 0) { __threadfence(); atomicExch(&flg[FMAC + o], 1u); }

  } else {
    // ---------- scan chunk c: expand own P~ in LDS + matvec + finisher ----------
    int c = b - B_SCAN0;                 // 0..127
    float* sTB = arena;                  // [40*41]
    float* sP  = arena + 1640;           // [40*41]
    float* u0A = arena + 3280;           // [40]
    float* u0B = arena + 3320;
    float* UhA = arena + 3360;           // [40*16]
    float* UpA = arena + 4000;
    float* UhB = arena + 4640;
    float* UpB = arena + 5280;
    float* hv  = arena + 5920;           // [6*16]
    float* hav = arena + 6016;
    float* hbv = arena + 6112;
    float* prA = arena + 6208;           // [6*40]
    float* aB  = arena + 6448;
    float* el  = arena + 6688;
    float* sLA0= arena + 6928;           // [40]
    if (tid == 0) lastFlag = 0;

    int s0 = 4*c;
    int len = min(4, 511 - s0);
    int w0 = (s0 >= 2) ? s0 - 2 : 0;
    int warmN = s0 - w0;                 // 0 (c==0) or 2
    int nst = warmN + len;

    // stage UA/UB columns (global-only deps)
    for (int idx = tid; idx < KK*33; idx += 256) {
      int r = idx / 33, k = idx % 33;
      int col = (k == 0) ? 0 : ((k < 17) ? k : 273 + (k - 17));
      float a = UA[r*289 + col];
      float bb2 = UB[r*289 + col];
      if (k == 0)      { u0A[r] = a; u0B[r] = bb2; }
      else if (k < 17) { UhA[r*16 + k - 1] = a; UhB[r*16 + k - 1] = bb2; }
      else             { UpA[r*16 + k - 17] = a; UpB[r*16 + k - 17] = bb2; }
    }

    // poll stage-1 dependencies: gather rows, TB, RNN chunks
    {
      int gmax = min(s0 + len, NN - 1);
      int cmin = w0 >> 3, cmax = (s0 + len - 1) >> 3;
      int jmin = max(w0 - 1, 1), jmax = max(s0 + len - 2, jmin);
      int bmin = (jmin - 1) >> 3, bmax = (jmax - 1) >> 3;
      if (tid < 8) { int rr = w0 + tid; if (rr <= gmax) waitflag(&flg[FG + rr]); }
      else if (tid == 8) waitflag(&flg[FTB]);
      else if (tid == 9) waitflag(&flg[FRC + cmin]);
      else if (tid == 10) waitflag(&flg[FRC + cmax]);
      else if (tid == 11) waitflag(&flg[FRC + 64 + bmin]);
      else if (tid == 12) waitflag(&flg[FRC + 64 + bmax]);
      else if (tid == 13 && c == 127) waitflag(&flg[FRC + 63]);
      else if (tid == 14 && c == 127) waitflag(&flg[FRC + 64 + 63]);
      else if (tid == 15 && c == 0) waitflag(&flg[FG]);   // WBG row 0 for LA0
    }
    __syncthreads();
    __threadfence();

    for (int idx = tid; idx < KK*KK; idx += 256)
      sTB[(idx/KK)*41 + (idx%KK)] = ws[OFF_TB + idx];
    for (int idx = tid; idx < nst*16; idx += 256) {
      int p = idx / 16, k = idx % 16;
      int i = w0 + 1 + p;
      hv[p*16 + k]  = ws[OFF_H + i*HH + k];
      hav[p*16 + k] = (i >= 2) ? ws[OFF_HP + (i - 2)*HH + k] : 0.f;
      hbv[p*16 + k] = ws[OFF_HP + (i - 1)*HH + k];
    }
    __syncthreads();
    for (int idx = tid; idx < nst*KK; idx += 256) {
      int p = idx / KK, r = idx % KK;
      int i = w0 + 1 + p;
      float accA = u0A[r];
      float accB = u0B[r] + ws[OFF_WPB + (i - 1)*KK + r];
      #pragma unroll
      for (int k2 = 0; k2 < HH; ++k2) {
        accA += hv[p*16 + k2]*UhA[r*16 + k2] + hav[p*16 + k2]*UpA[r*16 + k2];
        accB += hv[p*16 + k2]*UhB[r*16 + k2] + hbv[p*16 + k2]*UpB[r*16 + k2];
      }
      prA[p*KK + r] = accA; aB[p*KK + r] = accB;
    }
    __syncthreads();
    for (int idx = tid; idx < nst*KK; idx += 256) {
      int p = idx / KK, t = idx % KK;
      int i = w0 + 1 + p;
      float accB = aB[p*KK + t];
      const float* wbg = ws + OFF_WBG + i*KK;
      float e = 0.f;
      for (int u = 0; u < KK; ++u) e += wbg[u] * sigm(accB + sTB[t*41 + u]);
      el[p*KK + t] = e;
    }
    // poll MAC (A-tables)
    if (tid < KK) waitflag(&flg[FMAC + tid]);
    __syncthreads();
    __threadfence();

    if (c == 0 && tid < KK) {            // LA0 (i=0, r=BOS=0)
      int o = tid;
      float accB0 = u0B[o];
      float e0 = 0.f;
      for (int u = 0; u < KK; ++u) e0 += ws[OFF_WBG + u] * sigm(accB0 + sTB[o*41 + u]);
      float d = u0A[0] - X0C;
      float lp = ((ws[OFF_A3 + o*KK]*d + ws[OFF_A2 + o*KK])*d + ws[OFF_A1 + o*KK])*d
                 + ws[OFF_A0 + o*KK];
      sLA0[o] = lp + e0;
    }
    if (c == 127 && tid >= 64 && tid < 64 + KK) {   // FIN (i=512, o=EOS=1)
      int r = tid - 64;
      float accA = u0A[r];
      #pragma unroll
      for (int k2 = 0; k2 < HH; ++k2)
        accA += ws[OFF_H + 512*HH + k2]*UhA[r*16 + k2]
              + ws[OFF_HP + 510*HH + k2]*UpA[r*16 + k2];
      float d = accA - X0C;
      float lp = ((ws[OFF_A3 + KK + r]*d + ws[OFF_A2 + KK + r])*d + ws[OFF_A1 + KK + r])*d
                 + ws[OFF_A0 + KK + r];
      ws[OFF_FIN + r] = lp;
    }
    __syncthreads();

    float v = 1.f, lacc = 0.f;
    int cnt = 0;
    int o = min(lane, KK - 1);
    if (c == 0 && widx == 0) {
      float la = sLA0[o];
      float m0 = la;
      #pragma unroll
      for (int m = 1; m <= 32; m <<= 1) m0 = fmaxf(m0, __shfl_xor(m0, m));
      v = __expf(la - m0);
      lacc = m0;
    }
    for (int k = 0; k < nst; ++k) {
      for (int f = tid; f < KK*KK; f += 256) {
        int oo = f / KK, r = f - oo*KK;
        float d = prA[k*KK + r] - X0C;
        float lp = ((ws[OFF_A3 + f]*d + ws[OFF_A2 + f])*d + ws[OFF_A1 + f])*d
                   + ws[OFF_A0 + f];
        sP[oo*41 + r] = exp2f((lp + el[k*KK + oo])*LOG2E - SCB);
      }
      __syncthreads();
      if (widx == 0) {
        float a0 = 0, a1 = 0, a2 = 0, a3 = 0;
        #pragma unroll
        for (int r = 0; r < KK; r += 4) {
          a0 += __shfl(v, r + 0, 64)*sP[o*41 + r + 0];
          a1 += __shfl(v, r + 1, 64)*sP[o*41 + r + 1];
          a2 += __shfl(v, r + 2, 64)*sP[o*41 + r + 2];
          a3 += __shfl(v, r + 3, 64)*sP[o*41 + r + 3];
        }
        float s = (a0 + a1) + (a2 + a3);
        bool isReal = (k >= warmN);
        if (isReal) ++cnt;
        bool bound = (k == warmN - 1) || (k == nst - 1) ||
                     (isReal && (((k - warmN + 1) & 3) == 0));
        if (bound) {
          float mx = s;
          #pragma unroll
          for (int m = 1; m <= 32; m <<= 1) mx = fmaxf(mx, __shfl_xor(mx, m));
          v = s / mx;
          if (isReal) {
            lacc += __logf(mx) + (float)cnt*(SCB*LN2f);
            cnt = 0;
          }
        } else {
          v = s;
        }
      }
      __syncthreads();
    }
    if (widx == 0) {
      if (lane == 0) ws[OFF_LACC + c] = lacc;
      if (c == 127 && lane < KK) ws[OFF_VL + lane] = v;
    }
    __syncthreads();
    // hierarchical finisher arrival (max 16 same-address atomics)
    if (tid == 0) {
      __threadfence();
      unsigned* ctr = &flg[FCTR];
      unsigned s = atomicAdd(&ctr[1 + (c & 7)], 1u);
      if (s == 15u) {
        unsigned m = atomicAdd(&ctr[0], 1u);
        if (m == 7u) lastFlag = 1;
      }
    }
    __syncthreads();
    if (lastFlag && widx == 0) {
      __threadfence();
      float l = ws[OFF_LACC + lane] + ws[OFF_LACC + 64 + lane];
      #pragma unroll
      for (int m = 1; m <= 32; m <<= 1) l += __shfl_xor(l, m);
      float tv = (lane < KK) ? ws[OFF_VL + lane]*__expf(ws[OFF_FIN + lane]) : 0.f;
      #pragma unroll
      for (int m = 1; m <= 32; m <<= 1) tv += __shfl_xor(tv, m);
      if (lane == 0) out[0] = l + __logf(tv);
    }
  }
}

extern "C" void kernel_launch(void* const* d_in, const int* in_sizes, int n_in,
                              void* d_out, int out_size, void* d_ws, size_t ws_size,
                              hipStream_t stream) {
  const float* E     = (const float*)d_in[0];
  const float* M     = (const float*)d_in[1];
  const float* MP    = (const float*)d_in[2];
  const float* T     = (const float*)d_in[3];
  const float* UA    = (const float*)d_in[4];
  const float* UB    = (const float*)d_in[5];
  const float* WlinA = (const float*)d_in[6];
  const float* WlinB = (const float*)d_in[7];
  const int*   words = (const int*)d_in[8];
  float* ws  = (float*)d_ws;
  float* out = (float*)d_out;

  // zero all flags/counters (replay-safe graph node)
  hipMemsetAsync((char*)d_ws + (size_t)OFF_FLG*sizeof(float), 0,
                 768*sizeof(unsigned), stream);
  fused<<<dim3(NBLKS), dim3(256), 0, stream>>>(E, M, MP, T, UA, UB, WlinA, WlinB,
                                               words, ws, out);
}

// Round 12
// 60.616 us; speedup vs baseline: 1.3083x; 1.3083x over previous
//
#include <hip/hip_runtime.h>
#include <math.h>

#define KK 40
#define HH 16
#define DD 128
#define NN 512
#define X0C 0.085f
#define LOG2E 1.4426950408889634f
#define LN2f 0.6931471805599453f
#define SCB 17.0f   // per-step 2^-17 scaling folded into P~

// ws layout (float offsets). A-tables and PT stored TRANSPOSED ([o][r]).
enum {
  OFF_AW   = 0,                  // 512*16  fwd RNN drive
  OFF_BW   = OFF_AW + NN*HH,     // 512*16  bwd RNN drive
  OFF_WPB  = OFF_BW + NN*HH,     // 512*40  UwB @ W
  OFF_WBG  = OFF_WPB + NN*KK,    // 512*40  rowsum WlinB[words]
  OFF_TB   = OFF_WBG + NN*KK,    // 40*40
  OFF_H    = OFF_TB + KK*KK,     // 514*16
  OFF_HP   = OFF_H + 514*HH,     // 514*16
  OFF_A0   = OFF_HP + 514*HH,    // 40*40 x4 Taylor tables, layout [o][r]
  OFF_A1   = OFF_A0 + KK*KK,
  OFF_A2   = OFF_A1 + KK*KK,
  OFF_A3   = OFF_A2 + KK*KK,
  OFF_LA0  = OFF_A3 + KK*KK,     // 40
  OFF_FIN  = OFF_LA0 + KK,       // 40
  OFF_LACC = OFF_FIN + KK,       // 128 per-chunk log norms
  OFF_VL   = OFF_LACC + 128,     // 40 final direction
  OFF_CTR  = OFF_VL + 40,        // 16 uints: main ctr (0) + 8 sub-ctrs (1..8)
  OFF_D    = OFF_CTR + 16,       // 64000*4 sigma-derivative tables (16B aligned)
  OFF_PT   = OFF_D + KK*KK*KK*4, // 511*1600 P~^T matrices, layout [i][o][r]
  WS_FLOATS = OFF_PT + 511*KK*KK
};

__device__ __forceinline__ float sigm(float x) {
  return 1.f / (1.f + __expf(-x));
}

// KA: fused prep. Blocks 0..511: per-word gathers; block 512: TB = UtB@T^T +
//     zero finisher counters; blocks 513..552: sigma-derivative tables.
__global__ __launch_bounds__(256) void ka_prep(
    const float* __restrict__ E, const float* __restrict__ M, const float* __restrict__ MP,
    const float* __restrict__ T, const float* __restrict__ UA, const float* __restrict__ UB,
    const float* __restrict__ WlinB, const int* __restrict__ words, float* __restrict__ ws)
{
  int b = blockIdx.x, t = threadIdx.x;
  if (b < NN) {
    __shared__ float wrow[DD];
    int w = words[b];
    if (t < DD) wrow[t] = E[w*DD + t];
    if (t < KK) {                       // WBg[b,u] = sum_s WlinB[w, s*40+u]
      const float* wb = WlinB + (size_t)w*(KK*KK) + t;
      float acc = 0.f;
      #pragma unroll 8
      for (int s = 0; s < KK; ++s) acc += wb[s*KK];
      ws[OFF_WBG + b*KK + t] = acc;
    }
    __syncthreads();
    if (t < 16) {                       // aw: M[:,17:145] @ w
      float acc = 0.f; const float* mr = M + t*145 + 17;
      for (int d = 0; d < DD; ++d) acc += mr[d]*wrow[d];
      ws[OFF_AW + b*HH + t] = acc;
    } else if (t < 32) {                // bw: MP[:,1:129] @ w
      int j = t - 16; float acc = 0.f; const float* mr = MP + j*145 + 1;
      for (int d = 0; d < DD; ++d) acc += mr[d]*wrow[d];
      ws[OFF_BW + b*HH + j] = acc;
    } else if (t < 72) {                // wpartB: UB[:,145:273] @ w
      int o = t - 32; float acc = 0.f; const float* ur = UB + o*289 + 145;
      for (int d = 0; d < DD; ++d) acc += ur[d]*wrow[d];
      ws[OFF_WPB + b*KK + o] = acc;
    }
  } else if (b == NN) {                 // TB = UtB @ T^T + counter reset
    if (t < 16) ((unsigned*)(ws + OFF_CTR))[t] = 0u;
    __shared__ float Tl[KK*DD];
    for (int idx = t; idx < KK*DD; idx += 256) Tl[idx] = T[idx];
    __syncthreads();
    for (int out = t; out < KK*KK; out += 256) {
      int r = out / KK, s = out % KK;
      const float* ur = UB + r*289 + 145;
      float acc = 0.f;
      for (int d = 0; d < DD; ++d) acc += ur[d]*Tl[s*DD + d];
      ws[OFF_TB + out] = acc;
    }
  } else {                              // sigma-derivative tables, r = b-513
    int r = b - (NN + 1);
    __shared__ float ur[2*DD];
    __shared__ float sa[KK], ta[KK];
    if (t < DD) ur[t] = UA[r*289 + 17 + t];                 // UsA row
    else if (t < 2*DD) ur[t] = UA[r*289 + 145 + (t - DD)];  // UtA row
    __syncthreads();
    if (t < KK) {
      float acc = 0.f; const float* tr = T + t*DD;
      for (int d = 0; d < DD; ++d) acc += ur[d]*tr[d];
      sa[t] = acc;
    } else if (t >= 64 && t < 64 + KK) {
      int s = t - 64; float acc = 0.f; const float* tr = T + s*DD;
      for (int d = 0; d < DD; ++d) acc += ur[DD + d]*tr[d];
      ta[s] = acc;
    }
    __syncthreads();
    float4* dp = (float4*)(ws + OFF_D) + (size_t)r*1600;
    for (int st = t; st < KK*KK; st += 256) {
      int s = st / KK, u = st - s*KK;
      float y = X0C + sa[s] + ta[u];
      float sg = sigm(y);
      float s1 = sg*(1.f - sg);
      float d2 = s1*(1.f - 2.f*sg)*0.5f;
      float d3 = s1*(1.f - 6.f*sg*(1.f - sg))*(1.f/6.f);
      dp[st] = make_float4(sg, s1, d2, d3);
    }
  }
}

// KB: fused RNN + Taylor-MAC. Blocks 0..31: chunk-parallel RNN scans.
// Blocks 32..191: A_m[o][r] reductions (TRANSPOSED write).
__global__ __launch_bounds__(64) void kb_rnn_mac(const float* __restrict__ M,
                                                 const float* __restrict__ MP,
                                                 const float* __restrict__ WlinA,
                                                 float* __restrict__ ws)
{
  int b = blockIdx.x;
  int lane = threadIdx.x;
  if (b < 32) {
    // RNN: |dh'/dh| <= 0.04/step => 8 warm-up steps from 0: err ~7e-12.
    int row = lane & 15;
    int g = b*4 + (lane >> 4);          // 0..127
    int dirb = g >> 6;                  // 0 fwd, 1 bwd
    int c = g & 63;
    const float* Mat = dirb ? MP : M;
    const float* drv = ws + (dirb ? OFF_BW : OFF_AW);
    float* out = ws + (dirb ? OFF_HP : OFF_H);
    float base = Mat[row*145];
    int hoff = dirb ? 129 : 1;
    float mh[HH];
    #pragma unroll
    for (int k = 0; k < HH; ++k) mh[k] = Mat[row*145 + hoff + k];
    float dr[16];
    #pragma unroll
    for (int j = 0; j < 16; ++j) {
      int i = dirb ? (8*c + 15 - j) : (8*c - 8 + j);
      int ic = min(max(i, 0), NN - 1);
      dr[j] = drv[ic*HH + row];
    }
    float h = 0.f;
    #pragma unroll
    for (int j = 0; j < 16; ++j) {
      int i = dirb ? (8*c + 15 - j) : (8*c - 8 + j);
      bool valid = (i >= 0) && (i < NN);
      float acc = base + dr[j];
      #pragma unroll
      for (int k = 0; k < HH; ++k) acc += mh[k] * __shfl(h, k, 16);
      float h2 = sigm(acc);
      if (valid) h = h2;
      if (valid && j >= 8) out[(i + 1)*HH + row] = h;
    }
    if (b == 0 && lane < 16) {
      ws[OFF_H + lane] = 0.f;  ws[OFF_H + 513*HH + lane] = 0.f;
      ws[OFF_HP + lane] = 0.f; ws[OFF_HP + 513*HH + lane] = 0.f;
    }
  } else {
    // MAC: A_m[o][r] = sum_st D_m[r,st]*WlinA[o,st]; (o, r-quarter) per block.
    int bb = b - 32;
    int o = bb >> 2, q = bb & 3;
    int j = lane;
    float wreg[25];
    #pragma unroll
    for (int k = 0; k < 25; ++k) wreg[k] = WlinA[o*1600 + j + 64*k];
    for (int rr = 0; rr < 10; ++rr) {
      int r = q*10 + rr;
      const float4* dp = (const float4*)(ws + OFF_D) + (size_t)r*1600;
      float a0 = 0, a1 = 0, a2 = 0, a3 = 0;
      #pragma unroll
      for (int k = 0; k < 25; ++k) {
        float4 d = dp[j + 64*k];
        float wl = wreg[k];
        a0 += d.x*wl; a1 += d.y*wl; a2 += d.z*wl; a3 += d.w*wl;
      }
      #pragma unroll
      for (int m = 1; m <= 32; m <<= 1) {
        a0 += __shfl_xor(a0, m); a1 += __shfl_xor(a1, m);
        a2 += __shfl_xor(a2, m); a3 += __shfl_xor(a3, m);
      }
      if (j == 0) {                      // transposed write [o][r]
        ws[OFF_A0 + o*KK + r] = a0; ws[OFF_A1 + o*KK + r] = a1;
        ws[OFF_A2 + o*KK + r] = a2; ws[OFF_A3 + o*KK + r] = a3;
      }
    }
  }
}

// KD: fused per-position kernel. Block i (0..512):
//  - preA[r] and accB[t] from h/hp (exact); e[t] via 160-thread split
//  - cubic-Horner expansion; emit P~^T[i-1] ([o][r], coalesced), or LA0/FIN.
__global__ __launch_bounds__(256) void kd_expand(const float* __restrict__ UA,
                                                 const float* __restrict__ UB,
                                                 float* __restrict__ ws)
{
  int i = blockIdx.x;   // 0..512
  int tid = threadIdx.x;
  __shared__ float hl[16], hal[16], hbl[16];
  __shared__ float tbl[KK][KK + 1];
  __shared__ float wbg[KK];
  __shared__ float prA[KK], aB[KK], el[KK];
  __shared__ float ep[4][KK];
  bool hasE = (i < NN);
  if (tid < 16) {
    hl[tid]  = ws[OFF_H + i*HH + tid];
    hal[tid] = (i >= 2) ? ws[OFF_HP + (i - 2)*HH + tid] : 0.f;
    hbl[tid] = (i >= 1) ? ws[OFF_HP + (i - 1)*HH + tid] : 0.f;
  }
  if (hasE) {
    for (int idx = tid; idx < KK*KK; idx += 256) tbl[idx / KK][idx % KK] = ws[OFF_TB + idx];
    if (tid < KK) wbg[tid] = ws[OFF_WBG + i*KK + tid];
  }
  __syncthreads();
  if (tid < KK) {
    const float* ua = UA + tid*289;
    float accA = ua[0];
    #pragma unroll
    for (int k2 = 0; k2 < HH; ++k2) accA += hl[k2]*ua[1 + k2] + hal[k2]*ua[273 + k2];
    prA[tid] = accA;
    if (hasE) {
      const float* ub = UB + tid*289;
      float accB = ub[0] + ((i >= 1) ? ws[OFF_WPB + (i - 1)*KK + tid] : 0.f);
      #pragma unroll
      for (int k2 = 0; k2 < HH; ++k2) accB += hl[k2]*ub[1 + k2] + hbl[k2]*ub[273 + k2];
      aB[tid] = accB;
    }
  }
  __syncthreads();
  if (hasE && tid < 4*KK) {
    int t = tid % KK, g = tid / KK;
    float accB = aB[t];
    float p = 0.f;
    #pragma unroll
    for (int j = 0; j < 10; ++j) {
      int u = g*10 + j;
      p += wbg[u] * sigm(accB + tbl[t][u]);
    }
    ep[g][t] = p;
  }
  __syncthreads();
  if (tid < KK) el[tid] = hasE ? (ep[0][tid] + ep[1][tid] + ep[2][tid] + ep[3][tid]) : 0.f;
  __syncthreads();
  const float4* A0 = (const float4*)(ws + OFF_A0);   // [o][r] layout
  const float4* A1 = (const float4*)(ws + OFF_A1);
  const float4* A2 = (const float4*)(ws + OFF_A2);
  const float4* A3 = (const float4*)(ws + OFF_A3);
  float4* pt4 = (float4*)(ws + OFF_PT + (size_t)(i - 1)*1600);
  for (int f = tid; f < 400; f += 256) {
    int o = f / 10, rb = (f - o*10)*4;           // 4 consecutive r, fixed o
    float4 c0 = A0[f], c1 = A1[f], c2 = A2[f], c3 = A3[f];
    const float* p0 = (const float*)&c0; const float* p1 = (const float*)&c1;
    const float* p2 = (const float*)&c2; const float* p3 = (const float*)&c3;
    float res[4];
    float eo = el[o];
    #pragma unroll
    for (int j = 0; j < 4; ++j) {
      int r = rb + j;
      float d = prA[r] - X0C;
      float lp = ((p3[j]*d + p2[j])*d + p1[j])*d + p0[j];
      if (i == 0) {
        if (r == 0) ws[OFF_LA0 + o] = lp + eo;
        res[j] = 0.f;
      } else if (i == NN) {
        if (o == 1) ws[OFF_FIN + r] = lp;
        res[j] = 0.f;
      } else {
        res[j] = exp2f((lp + eo)*LOG2E - SCB);
      }
    }
    if (i > 0 && i < NN) pt4[f] = make_float4(res[0], res[1], res[2], res[3]);
  }
}

// KE: chunk-parallel vector scan (all-register, transposed coalesced loads) +
// hierarchical finisher (max 16 same-address atomics; the 128-flat-arrival tail
// was ~100ns x 128 serialized RMWs on the critical path).
__global__ __launch_bounds__(64) void ke_scan_fin(float* __restrict__ ws,
                                                  float* __restrict__ out)
{
  int c = blockIdx.x;           // 0..127
  int lane = threadIdx.x;
  int o = min(lane, KK - 1);    // lanes >=40 mirror column 39 (harmless dup)
  int s0 = 4*c;
  int len = min(4, 511 - s0);
  int w0 = (s0 >= 2) ? (s0 - 2) : 0;
  int warmN = s0 - w0;          // 0 (c==0) or 2
  int nst = warmN + len;        // 4, 5 or 6
  const float* P = ws + OFF_PT;
  float lacc = 0.f;
  float v;
  if (c == 0) {                 // exact start from la0
    float la = ws[OFF_LA0 + o];
    float m0 = la;
    #pragma unroll
    for (int m = 1; m <= 32; m <<= 1) m0 = fmaxf(m0, __shfl_xor(m0, m));
    v = __expf(la - m0);
    lacc = m0;
  } else {
    v = 1.f;
  }
  float pcA[KK], pcB[KK];
  int cnt = 0;

#define LOADCOL(buf, pi) do {                                       \
    const float4* g_ = (const float4*)(P + (size_t)(pi)*1600 + o*KK); \
    _Pragma("unroll")                                               \
    for (int q_ = 0; q_ < 10; ++q_) *(float4*)&buf[4*q_] = g_[q_];  \
  } while (0)

#define MSTEP(cur, nxt, k) do {                                 \
    if ((k) + 1 < nst) LOADCOL(nxt, w0 + (k) + 1);              \
    float a0_ = 0, a1_ = 0, a2_ = 0, a3_ = 0;                   \
    _Pragma("unroll")                                           \
    for (int r_ = 0; r_ < KK; r_ += 4) {                        \
      a0_ += __shfl(v, r_ + 0, 64)*cur[r_ + 0];                 \
      a1_ += __shfl(v, r_ + 1, 64)*cur[r_ + 1];                 \
      a2_ += __shfl(v, r_ + 2, 64)*cur[r_ + 2];                 \
      a3_ += __shfl(v, r_ + 3, 64)*cur[r_ + 3];                 \
    }                                                           \
    float s_ = (a0_ + a1_) + (a2_ + a3_);                       \
    bool isReal_ = (k) >= warmN;                                \
    if (isReal_) ++cnt;                                         \
    bool bound_ = ((k) == warmN - 1) || ((k) == nst - 1) ||     \
                  (isReal_ && (((k) - warmN + 1) & 3) == 0);    \
    if (bound_) {                                               \
      float mx_ = s_;                                           \
      _Pragma("unroll")                                         \
      for (int m_ = 1; m_ <= 32; m_ <<= 1)                      \
        mx_ = fmaxf(mx_, __shfl_xor(mx_, m_));                  \
      v = s_ / mx_;                                             \
      if (isReal_) {                                            \
        lacc += __logf(mx_) + (float)cnt*(SCB*LN2f);            \
        cnt = 0;                                                \
      }                                                         \
    } else {                                                    \
      v = s_;                                                   \
    }                                                           \
  } while (0)

  LOADCOL(pcA, w0);
  int k = 0;
  while (k + 2 <= nst) {
    MSTEP(pcA, pcB, k);
    MSTEP(pcB, pcA, k + 1);
    k += 2;
  }
  if (k < nst) MSTEP(pcA, pcB, k);
#undef MSTEP
#undef LOADCOL

  if (lane == 0) ws[OFF_LACC + c] = lacc;
  if (c == 127 && lane < KK) ws[OFF_VL + lane] = v;
  __threadfence();
  int last = 0;
  if (lane == 0) {               // hierarchical arrival: 16 adds/sub, 8 on main
    unsigned* ctr = (unsigned*)(ws + OFF_CTR);
    unsigned s = atomicAdd(&ctr[1 + (c & 7)], 1u);
    if (s == 15u) {
      unsigned m = atomicAdd(&ctr[0], 1u);
      last = (m == 7u);
    }
  }
  last = __shfl(last, 0, 64);
  if (last) {
    __threadfence();
    float l = ws[OFF_LACC + lane] + ws[OFF_LACC + 64 + lane];
    #pragma unroll
    for (int m = 1; m <= 32; m <<= 1) l += __shfl_xor(l, m);
    float tv = (lane < KK) ? ws[OFF_VL + lane]*__expf(ws[OFF_FIN + lane]) : 0.f;
    #pragma unroll
    for (int m = 1; m <= 32; m <<= 1) tv += __shfl_xor(tv, m);
    if (lane == 0) out[0] = l + __logf(tv);
  }
}

extern "C" void kernel_launch(void* const* d_in, const int* in_sizes, int n_in,
                              void* d_out, int out_size, void* d_ws, size_t ws_size,
                              hipStream_t stream) {
  const float* E     = (const float*)d_in[0];
  const float* M     = (const float*)d_in[1];
  const float* MP    = (const float*)d_in[2];
  const float* T     = (const float*)d_in[3];
  const float* UA    = (const float*)d_in[4];
  const float* UB    = (const float*)d_in[5];
  const float* WlinA = (const float*)d_in[6];
  const float* WlinB = (const float*)d_in[7];
  const int*   words = (const int*)d_in[8];
  float* ws  = (float*)d_ws;
  float* out = (float*)d_out;

  ka_prep<<<dim3(NN + 1 + KK), dim3(256), 0, stream>>>(E, M, MP, T, UA, UB, WlinB, words, ws);
  kb_rnn_mac<<<dim3(192), dim3(64), 0, stream>>>(M, MP, WlinA, ws);
  kd_expand<<<dim3(NN + 1), dim3(256), 0, stream>>>(UA, UB, ws);
  ke_scan_fin<<<dim3(128), dim3(64), 0, stream>>>(ws, out);
}

// Round 13
// 59.651 us; speedup vs baseline: 1.3294x; 1.0162x over previous
//
#include <hip/hip_runtime.h>
#include <math.h>

#define KK 40
#define HH 16
#define DD 128
#define NN 512
#define X0C 0.085f
#define LOG2E 1.4426950408889634f
#define LN2f 0.6931471805599453f
#define SCB 17.0f   // per-step 2^-17 scaling folded into P~

// ws layout (float offsets). A-tables and PT stored TRANSPOSED ([o][r]).
enum {
  OFF_AW   = 0,                  // 512*16  fwd RNN drive
  OFF_BW   = OFF_AW + NN*HH,     // 512*16  bwd RNN drive
  OFF_WPB  = OFF_BW + NN*HH,     // 512*40  UwB @ W
  OFF_WBG  = OFF_WPB + NN*KK,    // 512*40  rowsum WlinB[words]
  OFF_TB   = OFF_WBG + NN*KK,    // 40*40
  OFF_A0   = OFF_TB + KK*KK,     // 40*40 x4 Taylor tables, layout [o][r]
  OFF_A1   = OFF_A0 + KK*KK,
  OFF_A2   = OFF_A1 + KK*KK,
  OFF_A3   = OFF_A2 + KK*KK,
  OFF_LA0  = OFF_A3 + KK*KK,     // 40
  OFF_FIN  = OFF_LA0 + KK,       // 40
  OFF_LACC = OFF_FIN + KK,       // 128 per-chunk log norms
  OFF_VL   = OFF_LACC + 128,     // 40 final direction
  OFF_CTR  = OFF_VL + 40,        // 16 uints: main ctr (0) + 8 sub-ctrs (1..8)
  OFF_PT   = OFF_CTR + 16,       // 511*1600 P~^T matrices, layout [i][o][r]
  WS_FLOATS = OFF_PT + 511*KK*KK
};

__device__ __forceinline__ float sigm(float x) {
  return 1.f / (1.f + __expf(-x));
}

// K1 (64-thread blocks, 676 total, all independent):
//  b<512   : per-word gathers (WBG, aw, bw, wpartB)
//  512..515: TB quarter-blocks (b==512 also zeros finisher counters)
//  516..675: MAC self-contained: sa/ta in-block + on-the-fly sigma-derivs ->
//            A_m[o][r] (no D tables, no kb dependency).
__global__ __launch_bounds__(64) void k1_prep(
    const float* __restrict__ E, const float* __restrict__ M, const float* __restrict__ MP,
    const float* __restrict__ T, const float* __restrict__ UA, const float* __restrict__ UB,
    const float* __restrict__ WlinA, const float* __restrict__ WlinB,
    const int* __restrict__ words, float* __restrict__ ws)
{
  __shared__ __align__(16) float sm[8640];   // 34.6 KB arena
  int b = blockIdx.x, lane = threadIdx.x;

  if (b < NN) {
    // ---------------- gathers ----------------
    float* wrow = sm;                   // [128]
    int w = words[b];
    wrow[lane] = E[w*DD + lane];
    wrow[lane + 64] = E[w*DD + 64 + lane];
    if (lane < KK) {                    // WBg[b,u] = sum_s WlinB[w, s*40+u]
      const float* wb = WlinB + (size_t)w*(KK*KK) + lane;
      float acc = 0.f;
      #pragma unroll 8
      for (int s = 0; s < KK; ++s) acc += wb[s*KK];
      ws[OFF_WBG + b*KK + lane] = acc;
    }
    __syncthreads();
    for (int dd = lane; dd < 72; dd += 64) {
      const float* rp; float* dst;
      if (dd < 16)      { rp = M  + dd*145 + 17;        dst = ws + OFF_AW + b*HH + dd; }
      else if (dd < 32) { rp = MP + (dd - 16)*145 + 1;  dst = ws + OFF_BW + b*HH + (dd - 16); }
      else              { rp = UB + (dd - 32)*289 + 145; dst = ws + OFF_WPB + b*KK + (dd - 32); }
      float acc = 0.f;
      #pragma unroll 8
      for (int k = 0; k < DD; ++k) acc += rp[k]*wrow[k];
      *dst = acc;
    }
  } else if (b < NN + 4) {
    // ---------------- TB quarter: rows qb*10..qb*10+9 ----------------
    int qb = b - NN;
    if (qb == 0 && lane < 16) ((unsigned*)(ws + OFF_CTR))[lane] = 0u;
    for (int dd = lane; dd < 400; dd += 64) {
      int r = qb*10 + dd / 40, s = dd % 40;
      const float* ur = UB + r*289 + 145;
      const float* tr = T + s*DD;
      float acc = 0.f;
      #pragma unroll 8
      for (int k = 0; k < DD; ++k) acc += ur[k]*tr[k];
      ws[OFF_TB + r*KK + s] = acc;
    }
  } else {
    // ---------------- MAC self-contained, (o, q) per block ----------------
    int idx = b - (NN + 4);
    int o = idx >> 2, q = idx & 3;
    float* Tl = sm;                     // [40][132] padded (bank-spread)
    float* ur = sm + 5280;              // [10][256]
    float* sa = sm + 7840;              // [10][40]
    float* ta = sm + 8240;              // [10][40]
    for (int x = lane; x < KK*DD; x += 64) {
      int s = x >> 7, k = x & 127;
      Tl[s*132 + k] = T[x];
    }
    for (int x = lane; x < 2560; x += 64) {
      int rr = x >> 8, c = x & 255;
      int r = q*10 + rr;
      ur[x] = UA[r*289 + ((c < 128) ? (17 + c) : (145 + c - 128))];
    }
    __syncthreads();
    for (int dd = lane; dd < 800; dd += 64) {
      int rr = dd / 80, rem = dd % 80, wh = rem / 40, s = rem % 40;
      const float4* u4 = (const float4*)&ur[rr*256 + wh*128];
      const float4* t4 = (const float4*)&Tl[s*132];
      float acc = 0.f;
      #pragma unroll
      for (int k = 0; k < 32; ++k) {
        float4 a = u4[k], t = t4[k];
        acc += a.x*t.x + a.y*t.y + a.z*t.z + a.w*t.w;
      }
      if (wh == 0) sa[rr*40 + s] = acc; else ta[rr*40 + s] = acc;
    }
    __syncthreads();
    float wreg[25];
    #pragma unroll
    for (int k = 0; k < 25; ++k) wreg[k] = WlinA[o*1600 + lane + 64*k];
    for (int rr = 0; rr < 10; ++rr) {
      int r = q*10 + rr;
      float a0 = 0, a1 = 0, a2 = 0, a3 = 0;
      #pragma unroll
      for (int k = 0; k < 25; ++k) {
        int st = lane + 64*k;
        int s = st / 40, u = st - s*40;
        float y = X0C + sa[rr*40 + s] + ta[rr*40 + u];
        float sg = sigm(y);
        float s1 = sg*(1.f - sg);
        float d2 = s1*(1.f - 2.f*sg)*0.5f;
        float d3 = s1*(1.f - 6.f*sg*(1.f - sg))*(1.f/6.f);
        float wl = wreg[k];
        a0 += sg*wl; a1 += s1*wl; a2 += d2*wl; a3 += d3*wl;
      }
      #pragma unroll
      for (int m = 1; m <= 32; m <<= 1) {
        a0 += __shfl_xor(a0, m); a1 += __shfl_xor(a1, m);
        a2 += __shfl_xor(a2, m); a3 += __shfl_xor(a3, m);
      }
      if (lane == 0) {                  // transposed write [o][r]
        ws[OFF_A0 + o*KK + r] = a0; ws[OFF_A1 + o*KK + r] = a1;
        ws[OFF_A2 + o*KK + r] = a2; ws[OFF_A3 + o*KK + r] = a3;
      }
    }
  }
}

// KD: per-position kernel with in-block RNN warm-up (kb eliminated).
//  lanes 0..15:  h[i]  = 8 fwd steps from 0 (contraction 0.04^8 ~ 7e-12)
//  lanes 16..31: hp[i-1] (9 steps) and hp[i-2] (+1 step); exact when clamped
//  then: preA/accB, e[t], cubic-Horner expansion -> PT^T[i-1] / LA0 / FIN.
__global__ __launch_bounds__(256) void kd_expand(const float* __restrict__ UA,
                                                 const float* __restrict__ UB,
                                                 const float* __restrict__ M,
                                                 const float* __restrict__ MP,
                                                 float* __restrict__ ws)
{
  int i = blockIdx.x;   // 0..512
  int tid = threadIdx.x;
  __shared__ float hl[16], hal[16], hbl[16];
  __shared__ float tbl[KK][KK + 1];
  __shared__ float wbg[KK];
  __shared__ float prA[KK], aB[KK], el[KK];
  __shared__ float ep[4][KK];
  bool hasE = (i < NN);
  if (hasE) {
    for (int idx = tid; idx < KK*KK; idx += 256) tbl[idx / KK][idx % KK] = ws[OFF_TB + idx];
    if (tid >= 32 && tid < 32 + KK) wbg[tid - 32] = ws[OFF_WBG + i*KK + (tid - 32)];
  }
  if (tid < 16) {
    // fwd warm-up: state H[i] (after steps 0..i-1)
    int row = tid;
    float base = M[row*145];
    float mh[HH];
    #pragma unroll
    for (int k = 0; k < HH; ++k) mh[k] = M[row*145 + 1 + k];
    int j0 = (i >= 8) ? (i - 8) : 0;
    float drv[8];
    #pragma unroll
    for (int k = 0; k < 8; ++k) {
      int jj = j0 + k; jj = (jj < NN - 1) ? jj : (NN - 1);
      drv[k] = ws[OFF_AW + jj*HH + row];
    }
    float h = 0.f;
    #pragma unroll
    for (int k = 0; k < 8; ++k) {
      int jj = j0 + k;
      if (jj < i) {
        float acc = base + drv[k];
        #pragma unroll
        for (int kk = 0; kk < HH; ++kk) acc += mh[kk]*__shfl(h, kk, 16);
        h = sigm(acc);
      }
    }
    hl[row] = h;
  } else if (tid < 32) {
    // bwd warm-up: HP[i-1] (state after processing pos i-2 backward) and HP[i-2]
    int row = tid - 16;
    float base = MP[row*145];
    float mh[HH];
    #pragma unroll
    for (int k = 0; k < HH; ++k) mh[k] = MP[row*145 + 129 + k];
    float hB = 0.f, hA = 0.f;
    if (i >= 2) {
      int q0 = (i + 6 < NN - 1) ? (i + 6) : (NN - 1);   // i-2+8 clamped
      int lo = (i >= 3) ? (i - 3) : (i - 2);
      float drv[10];
      #pragma unroll
      for (int k = 0; k < 10; ++k) {
        int pos = q0 - k; pos = (pos > 0) ? pos : 0;
        drv[k] = ws[OFF_BW + pos*HH + row];
      }
      float h = 0.f;
      #pragma unroll
      for (int k = 0; k < 10; ++k) {
        int pos = q0 - k;
        if (pos >= lo) {
          float acc = base + drv[k];
          #pragma unroll
          for (int kk = 0; kk < HH; ++kk) acc += mh[kk]*__shfl(h, kk, 16);
          h = sigm(acc);
          if (pos == i - 2) hB = h;
          if (pos == i - 3) hA = h;
        }
      }
    }
    hbl[row] = hB;
    hal[row] = hA;
  }
  __syncthreads();
  if (tid < KK) {
    const float* ua = UA + tid*289;
    float accA = ua[0];
    #pragma unroll
    for (int k2 = 0; k2 < HH; ++k2) accA += hl[k2]*ua[1 + k2] + hal[k2]*ua[273 + k2];
    prA[tid] = accA;
    if (hasE) {
      const float* ub = UB + tid*289;
      float accB = ub[0] + ((i >= 1) ? ws[OFF_WPB + (i - 1)*KK + tid] : 0.f);
      #pragma unroll
      for (int k2 = 0; k2 < HH; ++k2) accB += hl[k2]*ub[1 + k2] + hbl[k2]*ub[273 + k2];
      aB[tid] = accB;
    }
  }
  __syncthreads();
  if (hasE && tid < 4*KK) {
    int t = tid % KK, g = tid / KK;
    float accB = aB[t];
    float p = 0.f;
    #pragma unroll
    for (int j = 0; j < 10; ++j) {
      int u = g*10 + j;
      p += wbg[u] * sigm(accB + tbl[t][u]);
    }
    ep[g][t] = p;
  }
  __syncthreads();
  if (tid < KK) el[tid] = hasE ? (ep[0][tid] + ep[1][tid] + ep[2][tid] + ep[3][tid]) : 0.f;
  __syncthreads();
  const float4* A0 = (const float4*)(ws + OFF_A0);   // [o][r] layout
  const float4* A1 = (const float4*)(ws + OFF_A1);
  const float4* A2 = (const float4*)(ws + OFF_A2);
  const float4* A3 = (const float4*)(ws + OFF_A3);
  float4* pt4 = (float4*)(ws + OFF_PT + (size_t)(i - 1)*1600);
  for (int f = tid; f < 400; f += 256) {
    int o = f / 10, rb = (f - o*10)*4;           // 4 consecutive r, fixed o
    float4 c0 = A0[f], c1 = A1[f], c2 = A2[f], c3 = A3[f];
    const float* p0 = (const float*)&c0; const float* p1 = (const float*)&c1;
    const float* p2 = (const float*)&c2; const float* p3 = (const float*)&c3;
    float res[4];
    float eo = el[o];
    #pragma unroll
    for (int j = 0; j < 4; ++j) {
      int r = rb + j;
      float d = prA[r] - X0C;
      float lp = ((p3[j]*d + p2[j])*d + p1[j])*d + p0[j];
      if (i == 0) {
        if (r == 0) ws[OFF_LA0 + o] = lp + eo;
        res[j] = 0.f;
      } else if (i == NN) {
        if (o == 1) ws[OFF_FIN + r] = lp;
        res[j] = 0.f;
      } else {
        res[j] = exp2f((lp + eo)*LOG2E - SCB);
      }
    }
    if (i > 0 && i < NN) pt4[f] = make_float4(res[0], res[1], res[2], res[3]);
  }
}

// KE: chunk-parallel vector scan (all-register, transposed coalesced loads) +
// hierarchical finisher (max 16 same-address atomics).
__global__ __launch_bounds__(64) void ke_scan_fin(float* __restrict__ ws,
                                                  float* __restrict__ out)
{
  int c = blockIdx.x;           // 0..127
  int lane = threadIdx.x;
  int o = min(lane, KK - 1);    // lanes >=40 mirror column 39 (harmless dup)
  int s0 = 4*c;
  int len = min(4, 511 - s0);
  int w0 = (s0 >= 2) ? (s0 - 2) : 0;
  int warmN = s0 - w0;          // 0 (c==0) or 2
  int nst = warmN + len;        // 4, 5 or 6
  const float* P = ws + OFF_PT;
  float lacc = 0.f;
  float v;
  if (c == 0) {                 // exact start from la0
    float la = ws[OFF_LA0 + o];
    float m0 = la;
    #pragma unroll
    for (int m = 1; m <= 32; m <<= 1) m0 = fmaxf(m0, __shfl_xor(m0, m));
    v = __expf(la - m0);
    lacc = m0;
  } else {
    v = 1.f;
  }
  float pcA[KK], pcB[KK];
  int cnt = 0;

#define LOADCOL(buf, pi) do {                                       \
    const float4* g_ = (const float4*)(P + (size_t)(pi)*1600 + o*KK); \
    _Pragma("unroll")                                               \
    for (int q_ = 0; q_ < 10; ++q_) *(float4*)&buf[4*q_] = g_[q_];  \
  } while (0)

#define MSTEP(cur, nxt, k) do {                                 \
    if ((k) + 1 < nst) LOADCOL(nxt, w0 + (k) + 1);              \
    float a0_ = 0, a1_ = 0, a2_ = 0, a3_ = 0;                   \
    _Pragma("unroll")                                           \
    for (int r_ = 0; r_ < KK; r_ += 4) {                        \
      a0_ += __shfl(v, r_ + 0, 64)*cur[r_ + 0];                 \
      a1_ += __shfl(v, r_ + 1, 64)*cur[r_ + 1];                 \
      a2_ += __shfl(v, r_ + 2, 64)*cur[r_ + 2];                 \
      a3_ += __shfl(v, r_ + 3, 64)*cur[r_ + 3];                 \
    }                                                           \
    float s_ = (a0_ + a1_) + (a2_ + a3_);                       \
    bool isReal_ = (k) >= warmN;                                \
    if (isReal_) ++cnt;                                         \
    bool bound_ = ((k) == warmN - 1) || ((k) == nst - 1) ||     \
                  (isReal_ && (((k) - warmN + 1) & 3) == 0);    \
    if (bound_) {                                               \
      float mx_ = s_;                                           \
      _Pragma("unroll")                                         \
      for (int m_ = 1; m_ <= 32; m_ <<= 1)                      \
        mx_ = fmaxf(mx_, __shfl_xor(mx_, m_));                  \
      v = s_ / mx_;                                             \
      if (isReal_) {                                            \
        lacc += __logf(mx_) + (float)cnt*(SCB*LN2f);            \
        cnt = 0;                                                \
      }                                                         \
    } else {                                                    \
      v = s_;                                                   \
    }                                                           \
  } while (0)

  LOADCOL(pcA, w0);
  int k = 0;
  while (k + 2 <= nst) {
    MSTEP(pcA, pcB, k);
    MSTEP(pcB, pcA, k + 1);
    k += 2;
  }
  if (k < nst) MSTEP(pcA, pcB, k);
#undef MSTEP
#undef LOADCOL

  if (lane == 0) ws[OFF_LACC + c] = lacc;
  if (c == 127 && lane < KK) ws[OFF_VL + lane] = v;
  __threadfence();
  int last = 0;
  if (lane == 0) {               // hierarchical arrival: 16 adds/sub, 8 on main
    unsigned* ctr = (unsigned*)(ws + OFF_CTR);
    unsigned s = atomicAdd(&ctr[1 + (c & 7)], 1u);
    if (s == 15u) {
      unsigned m = atomicAdd(&ctr[0], 1u);
      last = (m == 7u);
    }
  }
  last = __shfl(last, 0, 64);
  if (last) {
    __threadfence();
    float l = ws[OFF_LACC + lane] + ws[OFF_LACC + 64 + lane];
    #pragma unroll
    for (int m = 1; m <= 32; m <<= 1) l += __shfl_xor(l, m);
    float tv = (lane < KK) ? ws[OFF_VL + lane]*__expf(ws[OFF_FIN + lane]) : 0.f;
    #pragma unroll
    for (int m = 1; m <= 32; m <<= 1) tv += __shfl_xor(tv, m);
    if (lane == 0) out[0] = l + __logf(tv);
  }
}

extern "C" void kernel_launch(void* const* d_in, const int* in_sizes, int n_in,
                              void* d_out, int out_size, void* d_ws, size_t ws_size,
                              hipStream_t stream) {
  const float* E     = (const float*)d_in[0];
  const float* M     = (const float*)d_in[1];
  const float* MP    = (const float*)d_in[2];
  const float* T     = (const float*)d_in[3];
  const float* UA    = (const float*)d_in[4];
  const float* UB    = (const float*)d_in[5];
  const float* WlinA = (const float*)d_in[6];
  const float* WlinB = (const float*)d_in[7];
  const int*   words = (const int*)d_in[8];
  float* ws  = (float*)d_ws;
  float* out = (float*)d_out;

  k1_prep<<<dim3(NN + 4 + 160), dim3(64), 0, stream>>>(E, M, MP, T, UA, UB,
                                                       WlinA, WlinB, words, ws);
  kd_expand<<<dim3(NN + 1), dim3(256), 0, stream>>>(UA, UB, M, MP, ws);
  ke_scan_fin<<<dim3(128), dim3(64), 0, stream>>>(ws, out);
}